// Round 6
// baseline (3984.722 us; speedup 1.0000x reference)
//
#include <hip/hip_runtime.h>
#include <hip/hip_bf16.h>

typedef __hip_bfloat16 bf16;
typedef __attribute__((ext_vector_type(4))) float f32x4;
typedef __attribute__((ext_vector_type(8))) short bf16x8;
typedef __attribute__((ext_vector_type(4))) short short4v;

#define B_ 64
#define T_ 250
#define D_ 768
#define H_ 12
#define DH_ 64
#define F_ 32
#define L_ 12
#define BT_ (B_*T_)   // 16000
#define BT_P 16128    // padded to 63*256 for BM=256 GEMM tiles
#define NF_ (H_*F_)   // 384
#define QKVN_ (3*D_)  // 2304

static __device__ __forceinline__ float b2f(short s) {
    union { float f; unsigned u; } z; z.u = ((unsigned)(unsigned short)s) << 16; return z.f;
}
static __device__ __forceinline__ short f2bs(float f) {
    bf16 b = __float2bfloat16(f);
    return *(short*)&b;
}

// ---------------- lengths (mask dtype autodetect: int32 / float32 / bool8) ----------------
__global__ void lengths_kernel(const unsigned char* __restrict__ mask, int* __restrict__ lengths) {
    __shared__ int not_i32, not_f32;
    const unsigned int* w = (const unsigned int*)mask;
    int tid = threadIdx.x;
    if (tid == 0) { not_i32 = 0; not_f32 = 0; }
    __syncthreads();
    int li = 0, lf = 0;
    for (int i = tid; i < 4000; i += 256) {
        unsigned int v = w[i];
        if (v > 1u) li = 1;
        if (v != 0u && v != 0x3F800000u) lf = 1;
    }
    if (li) not_i32 = 1;
    if (lf) not_f32 = 1;
    __syncthreads();
    int mode = (!not_i32) ? 0 : ((!not_f32) ? 1 : 2);
    if (tid < B_) {
        int cnt = 0;
        if (mode == 0) {
            const int* r = (const int*)mask + tid * T_;
            for (int t = 0; t < T_; ++t) cnt += (r[t] != 0);
        } else if (mode == 1) {
            const unsigned int* r = w + tid * T_;
            for (int t = 0; t < T_; ++t) cnt += (r[t] != 0);
        } else {
            const unsigned char* r = mask + tid * T_;
            for (int t = 0; t < T_; ++t) cnt += (r[t] != 0);
        }
        lengths[tid] = cnt;
    }
}

// ---------------- embedding: x f32 + xb bf16 shadow ----------------
__global__ void embed_kernel(const int* __restrict__ batch, const float* __restrict__ tok,
                             const float* __restrict__ pos, float* __restrict__ x,
                             bf16* __restrict__ xb) {
    int bt = blockIdx.x;
    int t = bt % T_;
    int tok_id = batch[bt];
    const float* tr = tok + (size_t)tok_id * D_;
    const float* pr = pos + (size_t)t * D_;
    float* xr = x + (size_t)bt * D_;
    bf16* xbr = xb + (size_t)bt * D_;
    for (int d = threadIdx.x; d < D_; d += 256) {
        float v = tr[d] + pr[d];
        xr[d] = v;
        xbr[d] = __float2bfloat16(v);
    }
}

// ---------------- ALL-layer weight transpose+cast: W f32 [K,N] -> Wt bf16 [N,K] ----------------
__global__ __launch_bounds__(256) void transpose_w_all(
    const float* __restrict__ Wq, const float* __restrict__ Wk, const float* __restrict__ Wv,
    const float* __restrict__ Wo, const float* __restrict__ W1, const float* __restrict__ W2,
    bf16* __restrict__ Wt)
{
    __shared__ float tile[32][33];
    int zz = blockIdx.z;
    int l = zz / 6, m = zz - l * 6;
    const float* src;
    switch (m) {
        case 0: src = Wq; break; case 1: src = Wk; break; case 2: src = Wv; break;
        case 3: src = Wo; break; case 4: src = W1; break; default: src = W2; break;
    }
    src += (size_t)l * D_ * D_;
    bf16* dst = Wt + (size_t)zz * D_ * D_;
    int k0 = blockIdx.y * 32, n0 = blockIdx.x * 32;
    int tx = threadIdx.x, ty = threadIdx.y;
#pragma unroll
    for (int i = 0; i < 4; ++i)
        tile[ty + i * 8][tx] = src[(size_t)(k0 + ty + i * 8) * D_ + n0 + tx];
    __syncthreads();
#pragma unroll
    for (int i = 0; i < 4; ++i)
        dst[(size_t)(n0 + ty + i * 8) * D_ + k0 + tx] = __float2bfloat16(tile[tx][ty + i * 8]);
}

// ---------------- pack qkv bias ----------------
__global__ void pack_bias(const float* __restrict__ bq, const float* __restrict__ bk,
                          const float* __restrict__ bv, float* __restrict__ qkvb) {
    int o = blockIdx.x * 256 + threadIdx.x;
    if (o >= L_ * QKVN_) return;
    int l = o / QKVN_, c = o - l * QKVN_;
    float v;
    if (c < D_) v = bq[l * D_ + c];
    else if (c < 2 * D_) v = bk[l * D_ + c - D_];
    else v = bv[l * D_ + c - 2 * D_];
    qkvb[o] = v;
}

// ---------------- pipelined MFMA GEMM for QKV, BM=256 BN=192 BK=64 (proven R4 skeleton) ----------------
#define GP_SLOT 28672
__global__ __launch_bounds__(512, 2) void gemm_pipe(
    const bf16* __restrict__ A, const bf16* __restrict__ Bt,
    const float* __restrict__ bias, bf16* __restrict__ C,
    int N, int lda, int ldc)
{
    __shared__ __attribute__((aligned(16))) short lds_s[2 * GP_SLOT];
    const int tid = threadIdx.x, lane = tid & 63, wave = tid >> 6;
    const int wm = wave >> 2, wn = wave & 3;
    const int rsel = lane & 15, kq = lane >> 4;

    const int gx = gridDim.x;
    const int nwg = gx * gridDim.y;
    int orig = blockIdx.y * gx + blockIdx.x;
    int q = nwg >> 3, r = nwg & 7;
    int xcd = orig & 7, idx = orig >> 3;
    int swz = (xcd < r) ? xcd * (q + 1) + idx : r * (q + 1) + (xcd - r) * q + idx;
    const int row0 = (swz / gx) * 256;
    const int col0 = (swz % gx) * 192;

    const int srow = wave * 8 + (lane >> 3);
    const int sblk = (lane & 7) ^ ((lane >> 3) & 7);
    const short* gA = (const short*)A + (size_t)(row0 + srow) * lda + sblk * 8;
    const short* gB = (const short*)Bt + (size_t)(col0 + srow) * 768 + sblk * 8;
    const int ldest = wave * 512;

    f32x4 acc[8][3];
#pragma unroll
    for (int i = 0; i < 8; ++i)
#pragma unroll
        for (int j = 0; j < 3; ++j) acc[i][j] = (f32x4){0.f, 0.f, 0.f, 0.f};

    auto STAGE = [&](int kt, int slot) {
        short* base = lds_s + slot * GP_SLOT;
        int kc = kt * 64;
#pragma unroll
        for (int j = 0; j < 4; ++j)
            __builtin_amdgcn_global_load_lds(
                (const __attribute__((address_space(1))) unsigned int*)(gA + (size_t)(j * 64) * lda + kc),
                (__attribute__((address_space(3))) unsigned int*)(base + j * 4096 + ldest), 16, 0, 0);
#pragma unroll
        for (int j = 0; j < 3; ++j)
            __builtin_amdgcn_global_load_lds(
                (const __attribute__((address_space(1))) unsigned int*)(gB + (size_t)(j * 64) * 768 + kc),
                (__attribute__((address_space(3))) unsigned int*)(base + 16384 + j * 4096 + ldest), 16, 0, 0);
    };

    auto COMPUTE = [&](int slot) {
        const short* sA = lds_s + slot * GP_SLOT;
        const short* sB = sA + 16384;
#pragma unroll
        for (int ks = 0; ks < 2; ++ks) {
            int kb = ks * 4 + kq;
            bf16x8 bv[3];
#pragma unroll
            for (int n = 0; n < 3; ++n) {
                int rowb = wn * 48 + n * 16 + rsel;
                bv[n] = *(const bf16x8*)(sB + rowb * 64 + ((kb ^ (rowb & 7)) << 3));
            }
#pragma unroll
            for (int mh = 0; mh < 2; ++mh) {
                bf16x8 av[4];
#pragma unroll
                for (int m2 = 0; m2 < 4; ++m2) {
                    int rowa = wm * 128 + (mh * 4 + m2) * 16 + rsel;
                    av[m2] = *(const bf16x8*)(sA + rowa * 64 + ((kb ^ (rowa & 7)) << 3));
                }
                __builtin_amdgcn_s_setprio(1);
#pragma unroll
                for (int m2 = 0; m2 < 4; ++m2)
#pragma unroll
                    for (int n = 0; n < 3; ++n)
                        acc[mh * 4 + m2][n] = __builtin_amdgcn_mfma_f32_16x16x32_bf16(
                            av[m2], bv[n], acc[mh * 4 + m2][n], 0, 0, 0);
                __builtin_amdgcn_s_setprio(0);
            }
        }
    };

    STAGE(0, 0); STAGE(1, 1);
    asm volatile("s_waitcnt vmcnt(7)" ::: "memory");
    __builtin_amdgcn_s_barrier();

    for (int t = 0; t < 12; ++t) {
        COMPUTE(t & 1);
        if (t < 11) {
            __builtin_amdgcn_s_barrier();
            if (t < 10) {
                STAGE(t + 2, t & 1);
                asm volatile("s_waitcnt vmcnt(7)" ::: "memory");
            } else {
                asm volatile("s_waitcnt vmcnt(0)" ::: "memory");
            }
            __builtin_amdgcn_s_barrier();
        }
    }

    float bj[3];
#pragma unroll
    for (int n = 0; n < 3; ++n) {
        int col = col0 + wn * 48 + n * 16 + rsel;
        bj[n] = bias ? bias[col] : 0.f;
    }
#pragma unroll
    for (int mi = 0; mi < 8; ++mi) {
#pragma unroll
        for (int rr = 0; rr < 4; ++rr) {
            int row = row0 + wm * 128 + mi * 16 + (kq << 2) + rr;
            size_t base = (size_t)row * ldc + col0 + wn * 48 + rsel;
#pragma unroll
            for (int n = 0; n < 3; ++n)
                C[base + n * 16] = __float2bfloat16(acc[mi][n][rr] + bj[n]);
        }
    }
}

// ---------------- full-row GEMM + fused epilogue: BM=64, BN=768, B streamed from L2 ----------------
// mode 0: C = A@Bt^T + bias (bf16, ldc);  mode 1: + exact GELU;
// mode 2: x = LN(x + A@Bt^T + bias) -> writes x f32 and xb bf16 (LN over full 768-row in-block)
__global__ __launch_bounds__(512, 1) void gemm_ln(
    const bf16* __restrict__ A, const bf16* __restrict__ Bt,
    const float* __restrict__ bias, int lda, int mode,
    bf16* __restrict__ Cout, int ldc,
    float* __restrict__ x, bf16* __restrict__ xb,
    const float* __restrict__ g, const float* __restrict__ bvec)
{
    __shared__ __attribute__((aligned(16))) short As[64 * 768];   // 96 KB, XOR-swizzled
    __shared__ float red[64][8][2];                                // 4 KB
    const int tid = threadIdx.x, lane = tid & 63, wave = tid >> 6;
    const int rsel = lane & 15, kq = lane >> 4;
    const int row0 = blockIdx.x * 64;

    // stage whole A tile (64 x 768) once; swizzled source (m173 pattern), linear LDS dest
    {
        const short* Ag0 = (const short*)A + (size_t)row0 * lda;
#pragma unroll
        for (int j = 0; j < 12; ++j) {
            int s = j * 512 + tid;
            int row = s / 96;
            int kbp = s - row * 96;
            int kb = (kbp & 0x78) | ((kbp & 7) ^ (row & 7));
            __builtin_amdgcn_global_load_lds(
                (const __attribute__((address_space(1))) unsigned int*)(Ag0 + (size_t)row * lda + kb * 8),
                (__attribute__((address_space(3))) unsigned int*)(As + (j * 512 + wave * 64) * 8), 16, 0, 0);
        }
    }
    asm volatile("s_waitcnt vmcnt(0)" ::: "memory");
    __syncthreads();

    // K-loop: zero barriers; A from LDS (2-way-free swizzle), B frags from global (L2-hot 1.2MB)
    const short* Bg = (const short*)Bt + (size_t)(wave * 96 + rsel) * 768 + kq * 8;
    f32x4 acc[4][6];
#pragma unroll
    for (int i = 0; i < 4; ++i)
#pragma unroll
        for (int j = 0; j < 6; ++j) acc[i][j] = (f32x4){0.f, 0.f, 0.f, 0.f};

    for (int kt = 0; kt < 24; ++kt) {
        int kb = kt * 4 + kq;
        bf16x8 av[4], bvv[6];
#pragma unroll
        for (int m = 0; m < 4; ++m) {
            int row = m * 16 + rsel;
            int kbp = (kb & 0x78) | ((kb & 7) ^ (row & 7));
            av[m] = *(const bf16x8*)(As + row * 768 + kbp * 8);
        }
#pragma unroll
        for (int nf = 0; nf < 6; ++nf)
            bvv[nf] = *(const bf16x8*)(Bg + (size_t)nf * 16 * 768 + kt * 32);
        __builtin_amdgcn_s_setprio(1);
#pragma unroll
        for (int m = 0; m < 4; ++m)
#pragma unroll
            for (int nf = 0; nf < 6; ++nf)
                acc[m][nf] = __builtin_amdgcn_mfma_f32_16x16x32_bf16(av[m], bvv[nf], acc[m][nf], 0, 0, 0);
        __builtin_amdgcn_s_setprio(0);
    }

    float bj[6];
#pragma unroll
    for (int nf = 0; nf < 6; ++nf) bj[nf] = bias[wave * 96 + nf * 16 + rsel];

    if (mode <= 1) {
#pragma unroll
        for (int m = 0; m < 4; ++m) {
#pragma unroll
            for (int rr = 0; rr < 4; ++rr) {
                int grow = row0 + m * 16 + kq * 4 + rr;
                if (grow >= BT_) continue;
                size_t base = (size_t)grow * ldc + wave * 96 + rsel;
#pragma unroll
                for (int nf = 0; nf < 6; ++nf) {
                    float v = acc[m][nf][rr] + bj[nf];
                    if (mode == 1) v = 0.5f * v * (1.0f + erff(v * 0.70710678118654752f));
                    Cout[base + nf * 16] = __float2bfloat16(v);
                }
            }
        }
        return;
    }

    // mode 2: residual add (f32 x) + per-row LN across the full 768 cols
    float gv[6], bv2[6];
#pragma unroll
    for (int nf = 0; nf < 6; ++nf) {
        int col = wave * 96 + nf * 16 + rsel;
        gv[nf] = g[col]; bv2[nf] = bvec[col];
    }
#pragma unroll
    for (int m = 0; m < 4; ++m) {
#pragma unroll
        for (int rr = 0; rr < 4; ++rr) {
            int rl = m * 16 + kq * 4 + rr;
            int grow = row0 + rl;
            float s = 0.f, ss = 0.f;
#pragma unroll
            for (int nf = 0; nf < 6; ++nf) {
                float rv = (grow < BT_) ? x[(size_t)grow * D_ + wave * 96 + nf * 16 + rsel] : 0.f;
                float v = acc[m][nf][rr] + bj[nf] + rv;
                acc[m][nf][rr] = v;
                s += v; ss += v * v;
            }
#pragma unroll
            for (int o = 1; o < 16; o <<= 1) {
                s += __shfl_xor(s, o, 64);
                ss += __shfl_xor(ss, o, 64);
            }
            if (rsel == 0) { red[rl][wave][0] = s; red[rl][wave][1] = ss; }
        }
    }
    __syncthreads();
#pragma unroll
    for (int m = 0; m < 4; ++m) {
#pragma unroll
        for (int rr = 0; rr < 4; ++rr) {
            int rl = m * 16 + kq * 4 + rr;
            int grow = row0 + rl;
            if (grow >= BT_) continue;
            float S = 0.f, SS = 0.f;
#pragma unroll
            for (int w = 0; w < 8; ++w) { S += red[rl][w][0]; SS += red[rl][w][1]; }
            float mean = S * (1.f / D_);
            float var = SS * (1.f / D_) - mean * mean;
            float rstd = rsqrtf(var + 1e-5f);
            size_t base = (size_t)grow * D_ + wave * 96 + rsel;
#pragma unroll
            for (int nf = 0; nf < 6; ++nf) {
                float o = (acc[m][nf][rr] - mean) * rstd * gv[nf] + bv2[nf];
                x[base + nf * 16] = o;
                xb[base + nf * 16] = __float2bfloat16(o);
            }
        }
    }
}

// ---------------- features via MFMA, K=64 (block-diag omega) ----------------
__global__ __launch_bounds__(256) void feat_kernel(
    const bf16* __restrict__ qkv, const float* __restrict__ om,
    bf16* __restrict__ Qf, bf16* __restrict__ Kf, const int* __restrict__ lengths)
{
    __shared__ __attribute__((aligned(16))) short omT[32 * 64];   // [f][k]
    int z = blockIdx.z, h = blockIdx.y;
    int row0 = blockIdx.x * 128;
    int tid = threadIdx.x, lane = tid & 63, wave = tid >> 6;
    {
        int f = tid >> 3, k0 = (tid & 7) * 8;
#pragma unroll
        for (int j = 0; j < 8; ++j)
            omT[f * 64 + k0 + j] = f2bs(om[(size_t)(k0 + j) * F_ + f]);
    }
    __syncthreads();

    const short* A = (const short*)qkv + (size_t)z * D_ + h * DH_;
    int rsel = lane & 15, kof = (lane >> 4) << 3;

    bf16x8 af[2][2], bfr[2][2];
#pragma unroll
    for (int mi = 0; mi < 2; ++mi) {
        int row = row0 + wave * 32 + mi * 16 + rsel;
#pragma unroll
        for (int ks = 0; ks < 2; ++ks)
            af[mi][ks] = *(const bf16x8*)(A + (size_t)row * QKVN_ + ks * 32 + kof);
    }
#pragma unroll
    for (int ni = 0; ni < 2; ++ni)
#pragma unroll
        for (int ks = 0; ks < 2; ++ks)
            bfr[ni][ks] = *(const bf16x8*)(omT + (ni * 16 + rsel) * 64 + ks * 32 + kof);

    f32x4 acc[2][2];
#pragma unroll
    for (int i = 0; i < 2; ++i)
#pragma unroll
        for (int j = 0; j < 2; ++j) acc[i][j] = (f32x4){0.f, 0.f, 0.f, 0.f};
#pragma unroll
    for (int mi = 0; mi < 2; ++mi)
#pragma unroll
        for (int ni = 0; ni < 2; ++ni)
#pragma unroll
            for (int ks = 0; ks < 2; ++ks)
                acc[mi][ni] = __builtin_amdgcn_mfma_f32_16x16x32_bf16(af[mi][ks], bfr[ni][ks], acc[mi][ni], 0, 0, 0);

    bf16* out = z ? Kf : Qf;
#pragma unroll
    for (int mi = 0; mi < 2; ++mi) {
#pragma unroll
        for (int r = 0; r < 4; ++r) {
            int row = row0 + wave * 32 + mi * 16 + ((lane >> 4) << 2) + r;
            bool kill = false;
            if (z) { int b = row / T_; int t = row - b * T_; kill = (t >= lengths[b]); }
#pragma unroll
            for (int ni = 0; ni < 2; ++ni) {
                float v = fmaxf(acc[mi][ni][r], 0.f);
                if (kill) v = 0.f;
                out[(size_t)row * NF_ + h * F_ + ni * 16 + rsel] = __float2bfloat16(v);
            }
        }
    }
}

// ---------------- fused KV+Ksum+attn-out: one block per (b,h), KVt through LDS ----------------
__global__ __launch_bounds__(256) void kvattn_kernel(
    const bf16* __restrict__ Kf, const bf16* __restrict__ v, int ldv,
    const bf16* __restrict__ Qf, float* __restrict__ Z,
    bf16* __restrict__ out, int ldo)
{
    __shared__ short KfS[64][36];
    __shared__ short vS[64][68];
    __shared__ short KVtS[80][40];   // rows: 64 m-cols + Ksum(64) + 15 unread; stride 80B (2-way-free)
    int h = blockIdx.x, b = blockIdx.y;
    int tid = threadIdx.x, lane = tid & 63, wv = tid >> 6;
    int lr = tid >> 2, cp = tid & 3;
    int rsel = lane & 15, kq = lane >> 4;

    const short* Kg = (const short*)Kf + (size_t)(b * T_) * NF_ + h * F_;
    const short* Vg = (const short*)v + (size_t)(b * T_) * ldv + h * DH_;

    f32x4 acc[2];
    acc[0] = (f32x4){0.f, 0.f, 0.f, 0.f};
    acc[1] = (f32x4){0.f, 0.f, 0.f, 0.f};
    float ksacc = 0.f;

    for (int s0 = 0; s0 < T_; s0 += 64) {
        __syncthreads();
        int s = s0 + lr;
        if (s < T_) {
            bf16x8 k8 = *(const bf16x8*)(Kg + (size_t)s * NF_ + cp * 8);
            *(short4v*)&KfS[lr][cp * 8]     = *((const short4v*)&k8);
            *(short4v*)&KfS[lr][cp * 8 + 4] = *((const short4v*)&k8 + 1);
            bf16x8 v8a = *(const bf16x8*)(Vg + (size_t)s * ldv + cp * 16);
            bf16x8 v8b = *(const bf16x8*)(Vg + (size_t)s * ldv + cp * 16 + 8);
            *(short4v*)&vS[lr][cp * 16]      = *((const short4v*)&v8a);
            *(short4v*)&vS[lr][cp * 16 + 4]  = *((const short4v*)&v8a + 1);
            *(short4v*)&vS[lr][cp * 16 + 8]  = *((const short4v*)&v8b);
            *(short4v*)&vS[lr][cp * 16 + 12] = *((const short4v*)&v8b + 1);
        } else {
            short4v zz = (short4v){0, 0, 0, 0};
            *(short4v*)&KfS[lr][cp * 8]     = zz;
            *(short4v*)&KfS[lr][cp * 8 + 4] = zz;
            *(short4v*)&vS[lr][cp * 16]      = zz;
            *(short4v*)&vS[lr][cp * 16 + 4]  = zz;
            *(short4v*)&vS[lr][cp * 16 + 8]  = zz;
            *(short4v*)&vS[lr][cp * 16 + 12] = zz;
        }
        __syncthreads();
        if (tid < 32) {
            float p0 = 0.f, p1 = 0.f;
            for (int ss = 0; ss < 64; ss += 2) {
                p0 += b2f(KfS[ss][tid]);
                p1 += b2f(KfS[ss + 1][tid]);
            }
            ksacc += p0 + p1;
        }
        bf16x8 af0[2], af1[2], bfr[2];
#pragma unroll
        for (int ks = 0; ks < 2; ++ks) {
            int sb = ks * 32 + (kq << 3);
#pragma unroll
            for (int j = 0; j < 8; ++j) {
                ((short*)&af0[ks])[j] = KfS[sb + j][rsel];
                ((short*)&af1[ks])[j] = KfS[sb + j][16 + rsel];
                ((short*)&bfr[ks])[j] = vS[sb + j][wv * 16 + rsel];
            }
        }
#pragma unroll
        for (int ks = 0; ks < 2; ++ks) {
            acc[0] = __builtin_amdgcn_mfma_f32_16x16x32_bf16(af0[ks], bfr[ks], acc[0], 0, 0, 0);
            acc[1] = __builtin_amdgcn_mfma_f32_16x16x32_bf16(af1[ks], bfr[ks], acc[1], 0, 0, 0);
        }
    }

    // write KVt (transposed, bf16) + Ksum row into LDS
    __syncthreads();
    {
        int m = wv * 16 + rsel;
#pragma unroll
        for (int mi = 0; mi < 2; ++mi)
#pragma unroll
            for (int r = 0; r < 4; ++r) {
                int f = mi * 16 + (kq << 2) + r;
                KVtS[m][f] = f2bs(acc[mi][r]);
            }
        if (tid < 32) KVtS[64][tid] = f2bs(ksacc);
    }
    __syncthreads();

    // attn-out: out[t][n] = z * sum_f Qf[t][f]*KVt[n][f]; zden = col 64
    const short* Qg = (const short*)Qf + h * F_;
    int t0 = wv * 64;
    int kof = kq << 3;

    bf16x8 af[4], bfr2[5];
#pragma unroll
    for (int mi = 0; mi < 4; ++mi) {
        int t = t0 + mi * 16 + rsel;
        if (t > T_ - 1) t = T_ - 1;
        af[mi] = *(const bf16x8*)(Qg + (size_t)(b * T_ + t) * NF_ + kof);
    }
#pragma unroll
    for (int ni = 0; ni < 5; ++ni)
        bfr2[ni] = *(const bf16x8*)(&KVtS[ni * 16 + rsel][kof]);

    f32x4 oacc[4][5];
#pragma unroll
    for (int i = 0; i < 4; ++i)
#pragma unroll
        for (int j = 0; j < 5; ++j) oacc[i][j] = (f32x4){0.f, 0.f, 0.f, 0.f};
#pragma unroll
    for (int mi = 0; mi < 4; ++mi)
#pragma unroll
        for (int ni = 0; ni < 5; ++ni)
            oacc[mi][ni] = __builtin_amdgcn_mfma_f32_16x16x32_bf16(af[mi], bfr2[ni], oacc[mi][ni], 0, 0, 0);

#pragma unroll
    for (int mi = 0; mi < 4; ++mi) {
#pragma unroll
        for (int r = 0; r < 4; ++r) {
            int t = t0 + mi * 16 + (kq << 2) + r;
            float zden = __shfl(oacc[mi][4][r], lane & 48, 64);
            float z = 1.0f / (zden + 1e-6f);
            if (t < T_) {
                if (rsel == 0) Z[(size_t)(b * T_ + t) * H_ + h] = z;
                size_t base = (size_t)(b * T_ + t) * ldo + h * DH_ + rsel;
#pragma unroll
                for (int ni = 0; ni < 4; ++ni)
                    out[base + ni * 16] = __float2bfloat16(oacc[mi][ni][r] * z);
            }
        }
    }
}

// ---------------- attn weights via MFMA (last layer only) ----------------
__global__ __launch_bounds__(256) void attnw_kernel(const bf16* __restrict__ Qf,
                                                    const bf16* __restrict__ Kf,
                                                    const float* __restrict__ Z,
                                                    float* __restrict__ out) {
    int tt = blockIdx.x;
    int bh = blockIdx.y;
    int b = bh / H_, h = bh - b * H_;
    int tid = threadIdx.x;
    int lane = tid & 63, w = tid >> 6;
    int t0 = tt * 64, s0 = w * 64;
    int kof = (lane >> 4) * 8;

    const short* Qs = (const short*)Qf;
    const short* Ks = (const short*)Kf;

    bf16x8 af[4], bfr[4];
#pragma unroll
    for (int mi = 0; mi < 4; ++mi) {
        int t = t0 + mi * 16 + (lane & 15);
        if (t > T_ - 1) t = T_ - 1;
        af[mi] = *(const bf16x8*)(Qs + ((size_t)(b * T_ + t) * H_ + h) * F_ + kof);
    }
#pragma unroll
    for (int ni = 0; ni < 4; ++ni) {
        int s = s0 + ni * 16 + (lane & 15);
        if (s > T_ - 1) s = T_ - 1;
        bfr[ni] = *(const bf16x8*)(Ks + ((size_t)(b * T_ + s) * H_ + h) * F_ + kof);
    }

    f32x4 acc[4][4];
#pragma unroll
    for (int i = 0; i < 4; ++i)
#pragma unroll
        for (int j = 0; j < 4; ++j) acc[i][j] = (f32x4){0.f, 0.f, 0.f, 0.f};
#pragma unroll
    for (int mi = 0; mi < 4; ++mi)
#pragma unroll
        for (int ni = 0; ni < 4; ++ni)
            acc[mi][ni] = __builtin_amdgcn_mfma_f32_16x16x32_bf16(af[mi], bfr[ni], acc[mi][ni], 0, 0, 0);

#pragma unroll
    for (int mi = 0; mi < 4; ++mi) {
#pragma unroll
        for (int r = 0; r < 4; ++r) {
            int t = t0 + mi * 16 + (lane >> 4) * 4 + r;
            if (t >= T_) continue;
            float z = Z[(size_t)(b * T_ + t) * H_ + h];
            size_t base = ((size_t)bh * T_ + t) * T_;
#pragma unroll
            for (int ni = 0; ni < 4; ++ni) {
                int s = s0 + ni * 16 + (lane & 15);
                if (s < T_) out[base + s] = acc[mi][ni][r] * z;
            }
        }
    }
}

// ---------------- CLS writeout ----------------
__global__ void cls_kernel(const float* __restrict__ x, float* __restrict__ out) {
    int o = blockIdx.x * 256 + threadIdx.x;
    if (o >= B_ * D_) return;
    int b = o / D_, d = o % D_;
    out[o] = x[(size_t)(b * T_) * D_ + d];
}

extern "C" void kernel_launch(void* const* d_in, const int* in_sizes, int n_in,
                              void* d_out, int out_size, void* d_ws, size_t ws_size,
                              hipStream_t stream) {
    const int*   batch = (const int*)d_in[0];
    const unsigned char* mask = (const unsigned char*)d_in[1];
    const float* tok  = (const float*)d_in[2];
    const float* pos  = (const float*)d_in[3];
    const float* Wq   = (const float*)d_in[4];
    const float* bq   = (const float*)d_in[5];
    const float* Wk   = (const float*)d_in[6];
    const float* bk   = (const float*)d_in[7];
    const float* Wv   = (const float*)d_in[8];
    const float* bv   = (const float*)d_in[9];
    const float* Wo   = (const float*)d_in[10];
    const float* bo   = (const float*)d_in[11];
    const float* omega= (const float*)d_in[12];
    const float* ln1g = (const float*)d_in[13];
    const float* ln1b = (const float*)d_in[14];
    const float* ln2g = (const float*)d_in[15];
    const float* ln2b = (const float*)d_in[16];
    const float* W1   = (const float*)d_in[17];
    const float* b1   = (const float*)d_in[18];
    const float* W2   = (const float*)d_in[19];
    const float* b2   = (const float*)d_in[20];

    float* out_cls  = (float*)d_out;                   // [B, D]
    float* out_attn = (float*)d_out + B_ * D_;         // [B, H, T, T]

    // workspace (~259 MB). qkv [BT_P,2304] column-slices:
    //   [0,768): q -> attn-out ; [768,1536): k ; [1536,2304): v -> FFN1 mid (GELU)
    char* wsb = (char*)d_ws;
    float* x   = (float*)wsb; wsb += (size_t)BT_ * D_ * 4;        // 49.2 MB
    bf16* xb   = (bf16*)wsb;  wsb += (size_t)BT_P * D_ * 2;       // 24.8 MB
    bf16* qkv  = (bf16*)wsb;  wsb += (size_t)BT_P * QKVN_ * 2;    // 74.3 MB
    bf16* Qf   = (bf16*)wsb;  wsb += (size_t)BT_ * NF_ * 2;       // 12.3 MB
    bf16* Kf   = (bf16*)wsb;  wsb += (size_t)BT_ * NF_ * 2;
    float* Z   = (float*)wsb; wsb += (size_t)BT_ * H_ * 4;
    bf16* Wt   = (bf16*)wsb;  wsb += (size_t)L_ * 6 * D_ * D_ * 2;      // 84.9 MB
    float* qkvb= (float*)wsb; wsb += (size_t)L_ * QKVN_ * 4;
    int* lengths = (int*)wsb; wsb += 256;

    lengths_kernel<<<1, 256, 0, stream>>>(mask, lengths);
    embed_kernel<<<BT_, 256, 0, stream>>>(batch, tok, pos, x, xb);
    pack_bias<<<(L_ * QKVN_ + 255) / 256, 256, 0, stream>>>(bq, bk, bv, qkvb);
    transpose_w_all<<<dim3(24, 24, 72), dim3(32, 8), 0, stream>>>(Wq, Wk, Wv, Wo, W1, W2, Wt);

    dim3 qkv_g(QKVN_ / 192, BT_P / 256);  // (12, 63)
    dim3 feat_g(BT_ / 128, H_, 2);        // (125, 12, 2)
    dim3 kv_g(H_, B_);                    // (12, 64)
    const int lnr_g = BT_P / 64;          // 252
    const size_t WS = (size_t)D_ * D_;

    for (int l = 0; l < L_; ++l) {
        const bf16* Wtl = Wt + (size_t)l * 6 * WS;

        // fused QKV: [BT,768] @ [2304,768]^T -> qkv [BT,2304]
        gemm_pipe<<<qkv_g, 512, 0, stream>>>(xb, Wtl, qkvb + l * QKVN_, qkv,
                                             QKVN_, D_, QKVN_);

        // features (K=64 per head, fused Q+K dispatch)
        feat_kernel<<<feat_g, 256, 0, stream>>>(qkv, omega + (size_t)l * DH_ * F_,
                                                Qf, Kf, lengths);

        // fused KV+Ksum+attn-out (KVt via LDS); writes attn-out into qkv[:,0:768)
        kvattn_kernel<<<kv_g, 256, 0, stream>>>(Kf, qkv + 2 * D_, QKVN_, Qf, Z, qkv, QKVN_);

        if (l == L_ - 1)
            attnw_kernel<<<dim3(4, B_ * H_), 256, 0, stream>>>(Qf, Kf, Z, out_attn);

        // Wo proj + residual + LN1 -> x, xb
        gemm_ln<<<lnr_g, 512, 0, stream>>>(qkv, Wtl + 3 * WS, bo + l * D_, QKVN_, 2,
                                           nullptr, 0, x, xb, ln1g + l * D_, ln1b + l * D_);
        // FFN1 (GELU): xb @ W1 -> qkv[:,1536:2304)
        gemm_ln<<<lnr_g, 512, 0, stream>>>(xb, Wtl + 4 * WS, b1 + l * D_, D_, 1,
                                           qkv + 2 * D_, QKVN_, nullptr, nullptr, nullptr, nullptr);
        // FFN2 + residual + LN2 -> x, xb
        gemm_ln<<<lnr_g, 512, 0, stream>>>(qkv + 2 * D_, Wtl + 5 * WS, b2 + l * D_, QKVN_, 2,
                                           nullptr, 0, x, xb, ln2g + l * D_, ln2b + l * D_);
    }

    cls_kernel<<<(B_ * D_ + 255) / 256, 256, 0, stream>>>(x, out_cls);
}

// Round 7
// 2927.628 us; speedup vs baseline: 1.3611x; 1.3611x over previous
//
#include <hip/hip_runtime.h>
#include <hip/hip_bf16.h>

typedef __hip_bfloat16 bf16;
typedef __attribute__((ext_vector_type(4))) float f32x4;
typedef __attribute__((ext_vector_type(8))) short bf16x8;
typedef __attribute__((ext_vector_type(4))) short short4v;

#define B_ 64
#define T_ 250
#define D_ 768
#define H_ 12
#define DH_ 64
#define F_ 32
#define L_ 12
#define BT_ (B_*T_)   // 16000
#define BT_P 16128    // padded to 63*256 for BM=256 GEMM tiles
#define NF_ (H_*F_)   // 384
#define QKVN_ 2304    // qkv row stride: [v | Qf | Kf | scratch]
#define QN_ 1536      // composed QKV GEMM output cols

static __device__ __forceinline__ float b2f(short s) {
    union { float f; unsigned u; } z; z.u = ((unsigned)(unsigned short)s) << 16; return z.f;
}
static __device__ __forceinline__ short f2bs(float f) {
    bf16 b = __float2bfloat16(f);
    return *(short*)&b;
}

// ---------------- lengths (mask dtype autodetect: int32 / float32 / bool8) ----------------
__global__ void lengths_kernel(const unsigned char* __restrict__ mask, int* __restrict__ lengths) {
    __shared__ int not_i32, not_f32;
    const unsigned int* w = (const unsigned int*)mask;
    int tid = threadIdx.x;
    if (tid == 0) { not_i32 = 0; not_f32 = 0; }
    __syncthreads();
    int li = 0, lf = 0;
    for (int i = tid; i < 4000; i += 256) {
        unsigned int v = w[i];
        if (v > 1u) li = 1;
        if (v != 0u && v != 0x3F800000u) lf = 1;
    }
    if (li) not_i32 = 1;
    if (lf) not_f32 = 1;
    __syncthreads();
    int mode = (!not_i32) ? 0 : ((!not_f32) ? 1 : 2);
    if (tid < B_) {
        int cnt = 0;
        if (mode == 0) {
            const int* r = (const int*)mask + tid * T_;
            for (int t = 0; t < T_; ++t) cnt += (r[t] != 0);
        } else if (mode == 1) {
            const unsigned int* r = w + tid * T_;
            for (int t = 0; t < T_; ++t) cnt += (r[t] != 0);
        } else {
            const unsigned char* r = mask + tid * T_;
            for (int t = 0; t < T_; ++t) cnt += (r[t] != 0);
        }
        lengths[tid] = cnt;
    }
}

// ---------------- embedding: x f32 + xb bf16 shadow ----------------
__global__ void embed_kernel(const int* __restrict__ batch, const float* __restrict__ tok,
                             const float* __restrict__ pos, float* __restrict__ x,
                             bf16* __restrict__ xb) {
    int bt = blockIdx.x;
    int t = bt % T_;
    int tok_id = batch[bt];
    const float* tr = tok + (size_t)tok_id * D_;
    const float* pr = pos + (size_t)t * D_;
    float* xr = x + (size_t)bt * D_;
    bf16* xbr = xb + (size_t)bt * D_;
    for (int d = threadIdx.x; d < D_; d += 256) {
        float v = tr[d] + pr[d];
        xr[d] = v;
        xbr[d] = __float2bfloat16(v);
    }
}

// ---------------- weight transpose+cast for Wv/Wo/W1/W2: f32 [K,N] -> bf16 [N,K] ----------------
// grid (24, 24, 4*L): zm 0:Wv->layer rows 0; 1:Wo->slot3; 2:W1->slot4; 3:W2->slot5
__global__ __launch_bounds__(256) void transpose_w_all(
    const float* __restrict__ Wv, const float* __restrict__ Wo,
    const float* __restrict__ W1, const float* __restrict__ W2,
    bf16* __restrict__ Wt)
{
    __shared__ float tile[32][33];
    int zz = blockIdx.z;
    int l = zz >> 2, m = zz & 3;
    const float* src;
    int slot;
    switch (m) {
        case 0: src = Wv; slot = 0; break;
        case 1: src = Wo; slot = 3; break;
        case 2: src = W1; slot = 4; break;
        default: src = W2; slot = 5; break;
    }
    src += (size_t)l * D_ * D_;
    bf16* dst = Wt + ((size_t)l * 6 + slot) * D_ * D_;
    int k0 = blockIdx.y * 32, n0 = blockIdx.x * 32;
    int tx = threadIdx.x, ty = threadIdx.y;
#pragma unroll
    for (int i = 0; i < 4; ++i)
        tile[ty + i * 8][tx] = src[(size_t)(k0 + ty + i * 8) * D_ + n0 + tx];
    __syncthreads();
#pragma unroll
    for (int i = 0; i < 4; ++i)
        dst[(size_t)(n0 + ty + i * 8) * D_ + k0 + tx] = __float2bfloat16(tile[tx][ty + i * 8]);
}

// ---------------- composed feature weights: WcompT[768 + qk*384 + h*32+f][c] = sum_j W[c][h*64+j]*om[j][f] ----------------
// grid (24 c-chunks of 32, H, 2*L), block 256. f32 accumulate, one bf16 round.
__global__ __launch_bounds__(256) void compose_w(
    const float* __restrict__ Wq, const float* __restrict__ Wk,
    const float* __restrict__ omega, bf16* __restrict__ Wt)
{
    __shared__ float omS[64][33];
    __shared__ float WS2[32][65];
    int zz = blockIdx.z;
    int l = zz >> 1, qk = zz & 1;
    int h = blockIdx.y;
    int c0 = blockIdx.x * 32;
    const float* W = (qk ? Wk : Wq) + (size_t)l * D_ * D_;
    const float* om = omega + (size_t)l * DH_ * F_;
    int tid = threadIdx.x;
    for (int i = tid; i < 64 * 32; i += 256) {
        int j = i >> 5, f = i & 31;
        omS[j][f] = om[j * F_ + f];
    }
    for (int i = tid; i < 32 * 64; i += 256) {
        int ci = i >> 6, j = i & 63;
        WS2[ci][j] = W[(size_t)(c0 + ci) * D_ + h * DH_ + j];
    }
    __syncthreads();
    int f = tid & 31, cg = tid >> 5;
    bf16* dst = Wt + (size_t)l * 6 * D_ * D_
              + (size_t)(D_ + qk * NF_ + h * F_ + f) * D_;
#pragma unroll
    for (int cc = 0; cc < 4; ++cc) {
        int ci = cg + cc * 8;
        float s = 0.f;
#pragma unroll
        for (int j = 0; j < 64; ++j) s += WS2[ci][j] * omS[j][f];
        dst[c0 + ci] = __float2bfloat16(s);
    }
}

// ---------------- composed bias: qkvb[l] = [bv(768) | bq@om(384) | bk@om(384)] ----------------
__global__ void pack_bias2(const float* __restrict__ bq, const float* __restrict__ bk,
                           const float* __restrict__ bv, const float* __restrict__ omega,
                           float* __restrict__ qkvb) {
    int o = blockIdx.x * 256 + threadIdx.x;
    if (o >= L_ * QN_) return;
    int l = o / QN_, c = o - l * QN_;
    float v;
    if (c < D_) v = bv[l * D_ + c];
    else {
        int qk = (c >= D_ + NF_);
        int n = c - D_ - qk * NF_;
        int h = n >> 5, f = n & 31;
        const float* b = (qk ? bk : bq) + l * D_ + h * DH_;
        const float* om = omega + (size_t)l * DH_ * F_;
        float s = 0.f;
        for (int j = 0; j < 64; ++j) s += b[j] * om[j * F_ + f];
        v = s;
    }
    qkvb[o] = v;
}

// ---------------- pipelined MFMA GEMM, BM=256 BN=192 BK=64, wave tile 128x48 (R4-proven) ----------------
// act: 0 none, 1 GELU, 2 relu, 3 relu+mask, 9 composite QKV (per-tile from col0)
#define GP_SLOT 28672
__global__ __launch_bounds__(512, 2) void gemm_pipe(
    const bf16* __restrict__ A, const bf16* __restrict__ Bt,
    const float* __restrict__ bias, bf16* __restrict__ C,
    int N, int lda, int ldc, int act, const int* __restrict__ lengths)
{
    __shared__ __attribute__((aligned(16))) short lds_s[2 * GP_SLOT];
    const int tid = threadIdx.x, lane = tid & 63, wave = tid >> 6;
    const int wm = wave >> 2, wn = wave & 3;
    const int rsel = lane & 15, kq = lane >> 4;

    const int gx = gridDim.x;
    const int nwg = gx * gridDim.y;
    int orig = blockIdx.y * gx + blockIdx.x;
    int q = nwg >> 3, r = nwg & 7;
    int xcd = orig & 7, idx = orig >> 3;
    int swz = (xcd < r) ? xcd * (q + 1) + idx : r * (q + 1) + (xcd - r) * q + idx;
    const int row0 = (swz / gx) * 256;
    const int col0 = (swz % gx) * 192;

    const int srow = wave * 8 + (lane >> 3);
    const int sblk = (lane & 7) ^ ((lane >> 3) & 7);
    const short* gA = (const short*)A + (size_t)(row0 + srow) * lda + sblk * 8;
    const short* gB = (const short*)Bt + (size_t)(col0 + srow) * 768 + sblk * 8;
    const int ldest = wave * 512;

    f32x4 acc[8][3];
#pragma unroll
    for (int i = 0; i < 8; ++i)
#pragma unroll
        for (int j = 0; j < 3; ++j) acc[i][j] = (f32x4){0.f, 0.f, 0.f, 0.f};

    auto STAGE = [&](int kt, int slot) {
        short* base = lds_s + slot * GP_SLOT;
        int kc = kt * 64;
#pragma unroll
        for (int j = 0; j < 4; ++j)
            __builtin_amdgcn_global_load_lds(
                (const __attribute__((address_space(1))) unsigned int*)(gA + (size_t)(j * 64) * lda + kc),
                (__attribute__((address_space(3))) unsigned int*)(base + j * 4096 + ldest), 16, 0, 0);
#pragma unroll
        for (int j = 0; j < 3; ++j)
            __builtin_amdgcn_global_load_lds(
                (const __attribute__((address_space(1))) unsigned int*)(gB + (size_t)(j * 64) * 768 + kc),
                (__attribute__((address_space(3))) unsigned int*)(base + 16384 + j * 4096 + ldest), 16, 0, 0);
    };

    auto COMPUTE = [&](int slot) {
        const short* sA = lds_s + slot * GP_SLOT;
        const short* sB = sA + 16384;
#pragma unroll
        for (int ks = 0; ks < 2; ++ks) {
            int kb = ks * 4 + kq;
            bf16x8 bv[3];
#pragma unroll
            for (int n = 0; n < 3; ++n) {
                int rowb = wn * 48 + n * 16 + rsel;
                bv[n] = *(const bf16x8*)(sB + rowb * 64 + ((kb ^ (rowb & 7)) << 3));
            }
#pragma unroll
            for (int mh = 0; mh < 2; ++mh) {
                bf16x8 av[4];
#pragma unroll
                for (int m2 = 0; m2 < 4; ++m2) {
                    int rowa = wm * 128 + (mh * 4 + m2) * 16 + rsel;
                    av[m2] = *(const bf16x8*)(sA + rowa * 64 + ((kb ^ (rowa & 7)) << 3));
                }
                __builtin_amdgcn_s_setprio(1);
#pragma unroll
                for (int m2 = 0; m2 < 4; ++m2)
#pragma unroll
                    for (int n = 0; n < 3; ++n)
                        acc[mh * 4 + m2][n] = __builtin_amdgcn_mfma_f32_16x16x32_bf16(
                            av[m2], bv[n], acc[mh * 4 + m2][n], 0, 0, 0);
                __builtin_amdgcn_s_setprio(0);
            }
        }
    };

    STAGE(0, 0); STAGE(1, 1);
    asm volatile("s_waitcnt vmcnt(7)" ::: "memory");
    __builtin_amdgcn_s_barrier();

    for (int t = 0; t < 12; ++t) {
        COMPUTE(t & 1);
        if (t < 11) {
            __builtin_amdgcn_s_barrier();
            if (t < 10) {
                STAGE(t + 2, t & 1);
                asm volatile("s_waitcnt vmcnt(7)" ::: "memory");
            } else {
                asm volatile("s_waitcnt vmcnt(0)" ::: "memory");
            }
            __builtin_amdgcn_s_barrier();
        }
    }

    int eact = act;
    if (act == 9) eact = (col0 < D_) ? 0 : ((col0 < D_ + NF_) ? 2 : 3);

    float bj[3];
#pragma unroll
    for (int n = 0; n < 3; ++n) {
        int col = col0 + wn * 48 + n * 16 + rsel;
        bj[n] = bias ? bias[col] : 0.f;
    }
#pragma unroll
    for (int mi = 0; mi < 8; ++mi) {
#pragma unroll
        for (int rr = 0; rr < 4; ++rr) {
            int row = row0 + wm * 128 + mi * 16 + (kq << 2) + rr;
            bool kill = false;
            if (eact == 3) { int b = row / T_; int t = row - b * T_; kill = (t >= lengths[b & 63]); }
            size_t base = (size_t)row * ldc + col0 + wn * 48 + rsel;
#pragma unroll
            for (int n = 0; n < 3; ++n) {
                float v = acc[mi][n][rr] + bj[n];
                if (eact == 1) v = 0.5f * v * (1.0f + erff(v * 0.70710678118654752f));
                else if (eact >= 2) v = fmaxf(v, 0.f);
                if (kill) v = 0.f;
                C[base + n * 16] = __float2bfloat16(v);
            }
        }
    }
}

// ---------------- fused KV+Ksum+attn-out: one block per (b,h), KVt through LDS ----------------
// Kf/Qf/v/out are column-slices of qkv, row strides passed in.
__global__ __launch_bounds__(256) void kvattn_kernel(
    const bf16* __restrict__ Kf, int ldkf, const bf16* __restrict__ v, int ldv,
    const bf16* __restrict__ Qf, int ldq, float* __restrict__ Z,
    bf16* __restrict__ out, int ldo)
{
    __shared__ short KfS[64][36];
    __shared__ short vS[64][68];
    __shared__ short KVtS[80][40];
    int h = blockIdx.x, b = blockIdx.y;
    int tid = threadIdx.x, lane = tid & 63, wv = tid >> 6;
    int lr = tid >> 2, cp = tid & 3;
    int rsel = lane & 15, kq = lane >> 4;

    const short* Kg = (const short*)Kf + (size_t)(b * T_) * ldkf + h * F_;
    const short* Vg = (const short*)v + (size_t)(b * T_) * ldv + h * DH_;

    f32x4 acc[2];
    acc[0] = (f32x4){0.f, 0.f, 0.f, 0.f};
    acc[1] = (f32x4){0.f, 0.f, 0.f, 0.f};
    float ksacc = 0.f;

    for (int s0 = 0; s0 < T_; s0 += 64) {
        __syncthreads();
        int s = s0 + lr;
        if (s < T_) {
            bf16x8 k8 = *(const bf16x8*)(Kg + (size_t)s * ldkf + cp * 8);
            *(short4v*)&KfS[lr][cp * 8]     = *((const short4v*)&k8);
            *(short4v*)&KfS[lr][cp * 8 + 4] = *((const short4v*)&k8 + 1);
            bf16x8 v8a = *(const bf16x8*)(Vg + (size_t)s * ldv + cp * 16);
            bf16x8 v8b = *(const bf16x8*)(Vg + (size_t)s * ldv + cp * 16 + 8);
            *(short4v*)&vS[lr][cp * 16]      = *((const short4v*)&v8a);
            *(short4v*)&vS[lr][cp * 16 + 4]  = *((const short4v*)&v8a + 1);
            *(short4v*)&vS[lr][cp * 16 + 8]  = *((const short4v*)&v8b);
            *(short4v*)&vS[lr][cp * 16 + 12] = *((const short4v*)&v8b + 1);
        } else {
            short4v zz = (short4v){0, 0, 0, 0};
            *(short4v*)&KfS[lr][cp * 8]     = zz;
            *(short4v*)&KfS[lr][cp * 8 + 4] = zz;
            *(short4v*)&vS[lr][cp * 16]      = zz;
            *(short4v*)&vS[lr][cp * 16 + 4]  = zz;
            *(short4v*)&vS[lr][cp * 16 + 8]  = zz;
            *(short4v*)&vS[lr][cp * 16 + 12] = zz;
        }
        __syncthreads();
        if (tid < 32) {
            float p0 = 0.f, p1 = 0.f;
            for (int ss = 0; ss < 64; ss += 2) {
                p0 += b2f(KfS[ss][tid]);
                p1 += b2f(KfS[ss + 1][tid]);
            }
            ksacc += p0 + p1;
        }
        bf16x8 af0[2], af1[2], bfr[2];
#pragma unroll
        for (int ks = 0; ks < 2; ++ks) {
            int sb = ks * 32 + (kq << 3);
#pragma unroll
            for (int j = 0; j < 8; ++j) {
                ((short*)&af0[ks])[j] = KfS[sb + j][rsel];
                ((short*)&af1[ks])[j] = KfS[sb + j][16 + rsel];
                ((short*)&bfr[ks])[j] = vS[sb + j][wv * 16 + rsel];
            }
        }
#pragma unroll
        for (int ks = 0; ks < 2; ++ks) {
            acc[0] = __builtin_amdgcn_mfma_f32_16x16x32_bf16(af0[ks], bfr[ks], acc[0], 0, 0, 0);
            acc[1] = __builtin_amdgcn_mfma_f32_16x16x32_bf16(af1[ks], bfr[ks], acc[1], 0, 0, 0);
        }
    }

    __syncthreads();
    {
        int m = wv * 16 + rsel;
#pragma unroll
        for (int mi = 0; mi < 2; ++mi)
#pragma unroll
            for (int r = 0; r < 4; ++r) {
                int f = mi * 16 + (kq << 2) + r;
                KVtS[m][f] = f2bs(acc[mi][r]);
            }
        if (tid < 32) KVtS[64][tid] = f2bs(ksacc);
    }
    __syncthreads();

    const short* Qg = (const short*)Qf + h * F_;
    int t0 = wv * 64;
    int kof = kq << 3;

    bf16x8 af[4], bfr2[5];
#pragma unroll
    for (int mi = 0; mi < 4; ++mi) {
        int t = t0 + mi * 16 + rsel;
        if (t > T_ - 1) t = T_ - 1;
        af[mi] = *(const bf16x8*)(Qg + (size_t)(b * T_ + t) * ldq + kof);
    }
#pragma unroll
    for (int ni = 0; ni < 5; ++ni)
        bfr2[ni] = *(const bf16x8*)(&KVtS[ni * 16 + rsel][kof]);

    f32x4 oacc[4][5];
#pragma unroll
    for (int i = 0; i < 4; ++i)
#pragma unroll
        for (int j = 0; j < 5; ++j) oacc[i][j] = (f32x4){0.f, 0.f, 0.f, 0.f};
#pragma unroll
    for (int mi = 0; mi < 4; ++mi)
#pragma unroll
        for (int ni = 0; ni < 5; ++ni)
            oacc[mi][ni] = __builtin_amdgcn_mfma_f32_16x16x32_bf16(af[mi], bfr2[ni], oacc[mi][ni], 0, 0, 0);

#pragma unroll
    for (int mi = 0; mi < 4; ++mi) {
#pragma unroll
        for (int r = 0; r < 4; ++r) {
            int t = t0 + mi * 16 + (kq << 2) + r;
            float zden = __shfl(oacc[mi][4][r], lane & 48, 64);
            float z = 1.0f / (zden + 1e-6f);
            if (t < T_) {
                if (rsel == 0) Z[(size_t)(b * T_ + t) * H_ + h] = z;
                size_t base = (size_t)(b * T_ + t) * ldo + h * DH_ + rsel;
#pragma unroll
                for (int ni = 0; ni < 4; ++ni)
                    out[base + ni * 16] = __float2bfloat16(oacc[mi][ni][r] * z);
            }
        }
    }
}

// ---------------- attn weights via MFMA (last layer only); Qf/Kf strided slices ----------------
__global__ __launch_bounds__(256) void attnw_kernel(const bf16* __restrict__ Qf,
                                                    const bf16* __restrict__ Kf, int ldf,
                                                    const float* __restrict__ Z,
                                                    float* __restrict__ out) {
    int tt = blockIdx.x;
    int bh = blockIdx.y;
    int b = bh / H_, h = bh - b * H_;
    int tid = threadIdx.x;
    int lane = tid & 63, w = tid >> 6;
    int t0 = tt * 64, s0 = w * 64;
    int kof = (lane >> 4) * 8;

    const short* Qs = (const short*)Qf + h * F_;
    const short* Ks = (const short*)Kf + h * F_;

    bf16x8 af[4], bfr[4];
#pragma unroll
    for (int mi = 0; mi < 4; ++mi) {
        int t = t0 + mi * 16 + (lane & 15);
        if (t > T_ - 1) t = T_ - 1;
        af[mi] = *(const bf16x8*)(Qs + (size_t)(b * T_ + t) * ldf + kof);
    }
#pragma unroll
    for (int ni = 0; ni < 4; ++ni) {
        int s = s0 + ni * 16 + (lane & 15);
        if (s > T_ - 1) s = T_ - 1;
        bfr[ni] = *(const bf16x8*)(Ks + (size_t)(b * T_ + s) * ldf + kof);
    }

    f32x4 acc[4][4];
#pragma unroll
    for (int i = 0; i < 4; ++i)
#pragma unroll
        for (int j = 0; j < 4; ++j) acc[i][j] = (f32x4){0.f, 0.f, 0.f, 0.f};
#pragma unroll
    for (int mi = 0; mi < 4; ++mi)
#pragma unroll
        for (int ni = 0; ni < 4; ++ni)
            acc[mi][ni] = __builtin_amdgcn_mfma_f32_16x16x32_bf16(af[mi], bfr[ni], acc[mi][ni], 0, 0, 0);

#pragma unroll
    for (int mi = 0; mi < 4; ++mi) {
#pragma unroll
        for (int r = 0; r < 4; ++r) {
            int t = t0 + mi * 16 + (lane >> 4) * 4 + r;
            if (t >= T_) continue;
            float z = Z[(size_t)(b * T_ + t) * H_ + h];
            size_t base = ((size_t)bh * T_ + t) * T_;
#pragma unroll
            for (int ni = 0; ni < 4; ++ni) {
                int s = s0 + ni * 16 + (lane & 15);
                if (s < T_) out[base + s] = acc[mi][ni][r] * z;
            }
        }
    }
}

// ---------------- x = LN(x + res); res has row stride ldr; writes f32 x and bf16 xb ----------------
__global__ __launch_bounds__(256) void ln_kernel(float* __restrict__ x, const bf16* __restrict__ res,
                                                 int ldr,
                                                 const float* __restrict__ g, const float* __restrict__ bb,
                                                 bf16* __restrict__ xb) {
    int bt = blockIdx.x, tid = threadIdx.x;
    float* xr = x + (size_t)bt * D_;
    const bf16* rr = res + (size_t)bt * ldr;
    float v[3]; float s = 0.f, ss = 0.f;
#pragma unroll
    for (int i = 0; i < 3; ++i) {
        int idx = tid + i * 256;
        float t = xr[idx] + __bfloat162float(rr[idx]);
        v[i] = t; s += t; ss += t * t;
    }
#pragma unroll
    for (int o = 1; o < 64; o <<= 1) { s += __shfl_xor(s, o, 64); ss += __shfl_xor(ss, o, 64); }
    __shared__ float red[4][2];
    int wave = tid >> 6, lane = tid & 63;
    if (lane == 0) { red[wave][0] = s; red[wave][1] = ss; }
    __syncthreads();
    s = red[0][0] + red[1][0] + red[2][0] + red[3][0];
    ss = red[0][1] + red[1][1] + red[2][1] + red[3][1];
    float mean = s * (1.f / D_);
    float var = ss * (1.f / D_) - mean * mean;
    float rstd = rsqrtf(var + 1e-5f);
    bf16* xbr = xb + (size_t)bt * D_;
#pragma unroll
    for (int i = 0; i < 3; ++i) {
        int idx = tid + i * 256;
        float o = (v[i] - mean) * rstd * g[idx] + bb[idx];
        xr[idx] = o;
        xbr[idx] = __float2bfloat16(o);
    }
}

// ---------------- CLS writeout ----------------
__global__ void cls_kernel(const float* __restrict__ x, float* __restrict__ out) {
    int o = blockIdx.x * 256 + threadIdx.x;
    if (o >= B_ * D_) return;
    int b = o / D_, d = o % D_;
    out[o] = x[(size_t)(b * T_) * D_ + d];
}

extern "C" void kernel_launch(void* const* d_in, const int* in_sizes, int n_in,
                              void* d_out, int out_size, void* d_ws, size_t ws_size,
                              hipStream_t stream) {
    const int*   batch = (const int*)d_in[0];
    const unsigned char* mask = (const unsigned char*)d_in[1];
    const float* tok  = (const float*)d_in[2];
    const float* pos  = (const float*)d_in[3];
    const float* Wq   = (const float*)d_in[4];
    const float* bq   = (const float*)d_in[5];
    const float* Wk   = (const float*)d_in[6];
    const float* bk   = (const float*)d_in[7];
    const float* Wv   = (const float*)d_in[8];
    const float* bv   = (const float*)d_in[9];
    const float* Wo   = (const float*)d_in[10];
    const float* bo   = (const float*)d_in[11];
    const float* omega= (const float*)d_in[12];
    const float* ln1g = (const float*)d_in[13];
    const float* ln1b = (const float*)d_in[14];
    const float* ln2g = (const float*)d_in[15];
    const float* ln2b = (const float*)d_in[16];
    const float* W1   = (const float*)d_in[17];
    const float* b1   = (const float*)d_in[18];
    const float* W2   = (const float*)d_in[19];
    const float* b2   = (const float*)d_in[20];

    float* out_cls  = (float*)d_out;                   // [B, D]
    float* out_attn = (float*)d_out + B_ * D_;         // [B, H, T, T]

    // workspace (~235 MB). qkv [BT_P, 2304] column-slices:
    //   [0,768): v -> Wo-out (ln1 res) -> FFN2 out (ln2 res)
    //   [768,1152): Qf   [1152,1536): Kf
    //   [1536,2304): attn-out -> FFN1 mid (GELU)
    char* wsb = (char*)d_ws;
    float* x   = (float*)wsb; wsb += (size_t)BT_ * D_ * 4;        // 49.2 MB
    bf16* xb   = (bf16*)wsb;  wsb += (size_t)BT_P * D_ * 2;       // 24.8 MB
    bf16* qkv  = (bf16*)wsb;  wsb += (size_t)BT_P * QKVN_ * 2;    // 74.3 MB
    float* Z   = (float*)wsb; wsb += (size_t)BT_ * H_ * 4;
    bf16* Wt   = (bf16*)wsb;  wsb += (size_t)L_ * 6 * D_ * D_ * 2;      // 84.9 MB
    float* qkvb= (float*)wsb; wsb += (size_t)L_ * QN_ * 4;
    int* lengths = (int*)wsb; wsb += 256;

    lengths_kernel<<<1, 256, 0, stream>>>(mask, lengths);
    embed_kernel<<<BT_, 256, 0, stream>>>(batch, tok, pos, x, xb);
    pack_bias2<<<(L_ * QN_ + 255) / 256, 256, 0, stream>>>(bq, bk, bv, omega, qkvb);
    transpose_w_all<<<dim3(24, 24, 4 * L_), dim3(32, 8), 0, stream>>>(Wv, Wo, W1, W2, Wt);
    compose_w<<<dim3(24, H_, 2 * L_), 256, 0, stream>>>(Wq, Wk, omega, Wt);

    dim3 qkv_g(QN_ / 192, BT_P / 256);    // (8, 63)
    dim3 dxd_g(D_ / 192, BT_P / 256);     // (4, 63)
    dim3 kv_g(H_, B_);                    // (12, 64)
    const size_t WS = (size_t)D_ * D_;

    for (int l = 0; l < L_; ++l) {
        const bf16* Wtl = Wt + (size_t)l * 6 * WS;

        // composed QKV: [BT,768] @ [1536,768]^T -> [v | relu Qf | relu+mask Kf]
        gemm_pipe<<<qkv_g, 512, 0, stream>>>(xb, Wtl, qkvb + l * QN_, qkv,
                                             QN_, D_, QKVN_, 9, lengths);

        // fused KV+Ksum+attn-out; writes attn-out into qkv[:,1536:2304)
        kvattn_kernel<<<kv_g, 256, 0, stream>>>(qkv + 1152, QKVN_, qkv, QKVN_,
                                                qkv + 768, QKVN_, Z,
                                                qkv + 1536, QKVN_);

        if (l == L_ - 1)
            attnw_kernel<<<dim3(4, B_ * H_), 256, 0, stream>>>(qkv + 768, qkv + 1152, QKVN_,
                                                               Z, out_attn);

        // Wo proj: reads attn-out [1536,2304), writes [0,768) (v dead)
        gemm_pipe<<<dxd_g, 512, 0, stream>>>(qkv + 1536, Wtl + 3 * WS, bo + l * D_, qkv,
                                             D_, QKVN_, QKVN_, 0, lengths);
        ln_kernel<<<BT_, 256, 0, stream>>>(x, qkv, QKVN_, ln1g + l * D_, ln1b + l * D_, xb);

        // FFN1 (GELU): xb @ W1 -> [1536,2304) (attn-out dead)
        gemm_pipe<<<dxd_g, 512, 0, stream>>>(xb, Wtl + 4 * WS, b1 + l * D_, qkv + 1536,
                                             D_, D_, QKVN_, 1, lengths);
        // FFN2: [1536,2304) @ W2 -> [0,768) (ln1 res consumed)
        gemm_pipe<<<dxd_g, 512, 0, stream>>>(qkv + 1536, Wtl + 5 * WS, b2 + l * D_, qkv,
                                             D_, QKVN_, QKVN_, 0, lengths);
        ln_kernel<<<BT_, 256, 0, stream>>>(x, qkv, QKVN_, ln2g + l * D_, ln2b + l * D_, xb);
    }

    cls_kernel<<<(B_ * D_ + 255) / 256, 256, 0, stream>>>(x, out_cls);
}